// Round 1
// 1657.365 us; speedup vs baseline: 1.1221x; 1.1221x over previous
//
#include <hip/hip_runtime.h>
#include <math.h>

#define NEG_INF (-INFINITY)

// Sizes
// HID=256, H=8, DH=32, N1=60, N2=240, N3=300, L=600, B=32, S=512, DBERT=768

__device__ __forceinline__ float dot4(const float4 a, const float4 b, float acc) {
    acc = fmaf(a.x, b.x, acc);
    acc = fmaf(a.y, b.y, acc);
    acc = fmaf(a.z, b.z, acc);
    acc = fmaf(a.w, b.w, acc);
    return acc;
}

// ---------------------------------------------------------------------------
// K1: text_enc = tanh(text_hidden @ Wt^T + bt)   [16384 x 768] x [256 x 768]^T
// grid 1024 blocks (16 rows each) x 256 threads (one output col each)
// ---------------------------------------------------------------------------
__global__ __launch_bounds__(256) void k_text_enc(const float* __restrict__ th,
                                                  const float* __restrict__ Wt,
                                                  const float* __restrict__ bt,
                                                  float* __restrict__ te) {
    __shared__ __align__(16) float As[16 * 768];   // 48 KB
    const int tid = threadIdx.x;
    const long r0 = (long)blockIdx.x * 16;
    const float4* g = (const float4*)(th + r0 * 768);
    float4* As4 = (float4*)As;
    for (int idx = tid; idx < 16 * 192; idx += 256) As4[idx] = g[idx];
    __syncthreads();
    float acc[16];
#pragma unroll
    for (int r = 0; r < 16; ++r) acc[r] = 0.f;
    const float4* wrow = (const float4*)(Wt + tid * 768);
    for (int j = 0; j < 192; ++j) {
        float4 w = wrow[j];
#pragma unroll
        for (int r = 0; r < 16; ++r) acc[r] = dot4(As4[r * 192 + j], w, acc[r]);
    }
    const float bias = bt[tid];
#pragma unroll
    for (int r = 0; r < 16; ++r)
        te[(r0 + r) * 256 + tid] = tanhf(acc[r] + bias);
}

// ---------------------------------------------------------------------------
// K2: le = label_feat @ Wl^T + bl   [600 x 768] -> [600 x 256]
// grid 150 blocks (4 rows) x 256 threads
// ---------------------------------------------------------------------------
__global__ __launch_bounds__(256) void k_le_init(const float* __restrict__ lf,
                                                 const float* __restrict__ Wl,
                                                 const float* __restrict__ bl,
                                                 float* __restrict__ le) {
    __shared__ __align__(16) float Ls[4 * 768];
    const int tid = threadIdx.x;
    const int l0 = blockIdx.x * 4;
    const float4* g = (const float4*)(lf + (long)l0 * 768);
    float4* Ls4 = (float4*)Ls;
    for (int idx = tid; idx < 4 * 192; idx += 256) Ls4[idx] = g[idx];
    __syncthreads();
    float acc[4] = {0.f, 0.f, 0.f, 0.f};
    const float4* wrow = (const float4*)(Wl + tid * 768);
    for (int j = 0; j < 192; ++j) {
        float4 w = wrow[j];
#pragma unroll
        for (int r = 0; r < 4; ++r) acc[r] = dot4(Ls4[r * 192 + j], w, acc[r]);
    }
    const float bias = bl[tid];
#pragma unroll
    for (int r = 0; r < 4; ++r) le[(l0 + r) * 256 + tid] = acc[r] + bias;
}

// ---------------------------------------------------------------------------
// K3: K/Q/V = per_type(le, W*) ; PAQ = Q·PA^T(per head) ; PMV = V·PM^T
// Layouts: Kb/PAQ/PMV as [h][l][32].  grid 150 (4 rows) x 256
// ---------------------------------------------------------------------------
__global__ __launch_bounds__(256) void k_qkv(const float* __restrict__ le,
                                             const float* __restrict__ WK,
                                             const float* __restrict__ WQ,
                                             const float* __restrict__ WV,
                                             const float* __restrict__ PA,
                                             const float* __restrict__ PM,
                                             float* __restrict__ Kb,
                                             float* __restrict__ PAQ,
                                             float* __restrict__ PMV) {
    __shared__ __align__(16) float les[4 * 256];
    __shared__ __align__(16) float qs[4 * 256];
    __shared__ __align__(16) float vs[4 * 256];
    const int tid = threadIdx.x;
    const int l0 = blockIdx.x * 4;
    const int t3 = (l0 < 60) ? 0 : ((l0 < 300) ? 1 : 2);
#pragma unroll
    for (int r = 0; r < 4; ++r) les[r * 256 + tid] = le[(l0 + r) * 256 + tid];
    __syncthreads();
    float ak[4] = {0, 0, 0, 0}, aq[4] = {0, 0, 0, 0}, av[4] = {0, 0, 0, 0};
    const float4* kw = (const float4*)(WK + t3 * 65536 + tid * 256);
    const float4* qw = (const float4*)(WQ + t3 * 65536 + tid * 256);
    const float4* vw = (const float4*)(WV + t3 * 65536 + tid * 256);
    const float4* le4 = (const float4*)les;
    for (int j = 0; j < 64; ++j) {
        float4 wk = kw[j], wq = qw[j], wv = vw[j];
#pragma unroll
        for (int r = 0; r < 4; ++r) {
            float4 a = le4[r * 64 + j];
            ak[r] = dot4(a, wk, ak[r]);
            aq[r] = dot4(a, wq, aq[r]);
            av[r] = dot4(a, wv, av[r]);
        }
    }
    const int h = tid >> 5, d = tid & 31;
#pragma unroll
    for (int r = 0; r < 4; ++r) {
        Kb[(h * 600 + l0 + r) * 32 + d] = ak[r];
        qs[r * 256 + tid] = aq[r];
        vs[r * 256 + tid] = av[r];
    }
    __syncthreads();
#pragma unroll
    for (int r = 0; r < 4; ++r) {
        float s1 = 0.f, s2 = 0.f;
        for (int d2 = 0; d2 < 32; ++d2) {
            const float pa = PA[d * 32 + d2];   // d == output index e here
            const float pm = PM[d * 32 + d2];
            s1 = fmaf(qs[r * 256 + h * 32 + d2], pa, s1);
            s2 = fmaf(vs[r * 256 + h * 32 + d2], pm, s2);
        }
        PAQ[(h * 600 + l0 + r) * 32 + d] = s1;
        PMV[(h * 600 + l0 + r) * 32 + d] = s2;
    }
}

// ---------------------------------------------------------------------------
// K4: Sc[h,q,:] = scale*PAQ[q,h]·K[:,h] ; zero-block ; +mask ; softmax ;
//     zero Watt on Z ; M[q, h*32+e] = sum_k Watt*PMV.  grid (600, 8) x 256
// ---------------------------------------------------------------------------
__global__ __launch_bounds__(256) void k_attn(const float* __restrict__ Kb,
                                              const float* __restrict__ PAQ,
                                              const float* __restrict__ PMV,
                                              const int* __restrict__ am,
                                              float* __restrict__ Mb) {
    __shared__ float sc[600];
    __shared__ float red[256];
    __shared__ __align__(16) float paqs[32];
    const int tid = threadIdx.x;
    const int q = blockIdx.x, h = blockIdx.y;
    if (tid < 32) paqs[tid] = PAQ[(h * 600 + q) * 32 + tid];
    __syncthreads();
    const float scale = 0.1767766952966369f;  // 1/sqrt(32)
    const bool qb1 = (q < 60), qb3 = (q >= 300);
    float lm = NEG_INF;
    for (int k = tid; k < 600; k += 256) {
        const float4* kr = (const float4*)(Kb + (h * 600 + k) * 32);
        const float4* pr = (const float4*)paqs;
        float dot = 0.f;
#pragma unroll
        for (int j = 0; j < 8; ++j) dot = dot4(pr[j], kr[j], dot);
        const bool zq = (qb1 && k >= 300) || (qb3 && k < 60);
        const float s = (zq ? 0.f : dot * scale) + ((am[q * 600 + k] == 0) ? NEG_INF : 0.f);
        sc[k] = s;
        lm = fmaxf(lm, s);
    }
    red[tid] = lm;
    __syncthreads();
    for (int off = 128; off > 0; off >>= 1) {
        if (tid < off) red[tid] = fmaxf(red[tid], red[tid + off]);
        __syncthreads();
    }
    const float mx = red[0];
    __syncthreads();
    float ls = 0.f;
    for (int k = tid; k < 600; k += 256) {
        const float p = __expf(sc[k] - mx);
        ls += p;   // denominator includes zero-block (pre-zeroed) positions
        const bool zq = (qb1 && k >= 300) || (qb3 && k < 60);
        sc[k] = zq ? 0.f : p;
    }
    red[tid] = ls;
    __syncthreads();
    for (int off = 128; off > 0; off >>= 1) {
        if (tid < off) red[tid] += red[tid + off];
        __syncthreads();
    }
    const float inv = 1.f / red[0];
    __syncthreads();
    const int e = tid & 31, c = tid >> 5;
    float part = 0.f;
    for (int k = c; k < 600; k += 8)
        part = fmaf(sc[k], PMV[(h * 600 + k) * 32 + e], part);
    red[tid] = part;
    __syncthreads();
    if (tid < 32) {
        float tot = 0.f;
#pragma unroll
        for (int cc = 0; cc < 8; ++cc) tot += red[cc * 32 + tid];
        Mb[q * 256 + h * 32 + tid] = tot * inv;
    }
}

// ---------------------------------------------------------------------------
// K5: le += tanh(per_type(M, WA))   grid 150 (4 rows) x 256
// ---------------------------------------------------------------------------
__global__ __launch_bounds__(256) void k_update(const float* __restrict__ Mb,
                                                const float* __restrict__ WA,
                                                float* __restrict__ le) {
    __shared__ __align__(16) float Ms[4 * 256];
    const int tid = threadIdx.x;
    const int l0 = blockIdx.x * 4;
    const int t3 = (l0 < 60) ? 0 : ((l0 < 300) ? 1 : 2);
#pragma unroll
    for (int r = 0; r < 4; ++r) Ms[r * 256 + tid] = Mb[(l0 + r) * 256 + tid];
    __syncthreads();
    float acc[4] = {0, 0, 0, 0};
    const float4* wrow = (const float4*)(WA + t3 * 65536 + tid * 256);
    const float4* M4 = (const float4*)Ms;
    for (int j = 0; j < 64; ++j) {
        float4 w = wrow[j];
#pragma unroll
        for (int r = 0; r < 4; ++r) acc[r] = dot4(M4[r * 64 + j], w, acc[r]);
    }
#pragma unroll
    for (int r = 0; r < 4; ++r) {
        const int i = (l0 + r) * 256 + tid;
        le[i] = tanhf(acc[r]) + le[i];
    }
}

// ---------------------------------------------------------------------------
// K6: fused label->text pooling.  block = (12 l-rows, one b), 256 threads.
//     Phase B v2: each thread owns 2 s-rows, reads te rows straight from
//     global (64B-line batches, L1-resident), les via wave-uniform LDS
//     broadcasts amortized over 2 rows -> 8 FMA per LDS read instead of 2.
//     No Ts staging / no per-chunk barriers in Phase B; padm in registers.
//     LDS 52.8 KB -> 3 blocks/CU.           grid (50, 32)
// ---------------------------------------------------------------------------
__global__ __launch_bounds__(256) void k_pool(const float* __restrict__ te,
                                              const float* __restrict__ le,
                                              const int* __restrict__ toks,
                                              float* __restrict__ feat) {
    __shared__ __align__(16) float les[12 * 256];   // 12 KB
    __shared__ float scs[12 * 512];                 // 24 KB
    __shared__ __align__(16) float Ts[16 * 256];    // 16 KB (Phase D staging)
    __shared__ float red[192];
    __shared__ float mxs[12];
    __shared__ float invs[12];
    const int tid = threadIdx.x;
    const int l0 = blockIdx.x * 12;
    const int b = blockIdx.y;

    // stage les (rows l0..l0+11 are contiguous in le)
    {
        const float4* leg = (const float4*)(le + (long)l0 * 256);
        float4* les4 = (float4*)les;
        for (int idx = tid; idx < 768; idx += 256) les4[idx] = leg[idx];
    }
    __syncthreads();

    // ---- Phase B: scores for s0 = tid, s1 = tid + 256 -------------------
    float acc0[12], acc1[12];
#pragma unroll
    for (int l = 0; l < 12; ++l) { acc0[l] = 0.f; acc1[l] = 0.f; }
    const float4* rowA = (const float4*)(te + (long)b * 131072 + (long)tid * 256);
    const float4* rowB = rowA + 64 * 256;   // +256 rows (64 float4 per row)
    const float4* lp = (const float4*)les;  // [12][64] float4
    for (int j0 = 0; j0 < 64; j0 += 4) {
        float4 ra[4], rb[4];
#pragma unroll
        for (int u = 0; u < 4; ++u) { ra[u] = rowA[j0 + u]; rb[u] = rowB[j0 + u]; }
#pragma unroll
        for (int l = 0; l < 12; ++l) {
#pragma unroll
            for (int u = 0; u < 4; ++u) {
                const float4 lv = lp[l * 64 + j0 + u];   // wave-uniform broadcast
                acc0[l] = dot4(lv, ra[u], acc0[l]);
                acc1[l] = dot4(lv, rb[u], acc1[l]);
            }
        }
    }
    {
        const int t0v = toks[b * 512 + tid];
        const int t1v = toks[b * 512 + 256 + tid];
        const float pm0 = (t0v == 0 || t0v == 101 || t0v == 102) ? NEG_INF : 0.f;
        const float pm1 = (t1v == 0 || t1v == 101 || t1v == 102) ? NEG_INF : 0.f;
#pragma unroll
        for (int l = 0; l < 12; ++l) {
            scs[l * 512 + tid]       = acc0[l] + pm0;
            scs[l * 512 + 256 + tid] = acc1[l] + pm1;
        }
    }
    __syncthreads();

    // ---- Phase C: softmax stats per l-row (max, unnormalized p, 1/denom) --
    const int g = tid >> 4, t16 = tid & 15;
    if (tid < 192) {
        float lm = NEG_INF;
        for (int j = 0; j < 32; ++j) lm = fmaxf(lm, scs[g * 512 + j * 16 + t16]);
        red[tid] = lm;
    }
    __syncthreads();
    if (tid < 12) {
        float m = NEG_INF;
        for (int t = 0; t < 16; ++t) m = fmaxf(m, red[tid * 16 + t]);
        mxs[tid] = m;
    }
    __syncthreads();
    if (tid < 192) {
        const float mval = mxs[g];
        float ls = 0.f;
        for (int j = 0; j < 32; ++j) {
            const int idx = g * 512 + j * 16 + t16;
            const float p = __expf(scs[idx] - mval);
            scs[idx] = p;
            ls += p;
        }
        red[tid] = ls;
    }
    __syncthreads();
    if (tid < 12) {
        float ssum = 0.f;
        for (int t = 0; t < 16; ++t) ssum += red[tid * 16 + t];
        invs[tid] = 1.f / ssum;
    }
    __syncthreads();

    // ---- Phase D: features[l, :] = (sum_s p * te[s,:]) * inv -------------
    const float4* teg = (const float4*)(te + (long)b * 131072);
    float4* T4 = (float4*)Ts;
    const int e4 = tid & 63;       // float4 column
    const int ig = tid >> 6;       // rows ig*3 .. ig*3+2
    float4 a0 = {0, 0, 0, 0}, a1 = {0, 0, 0, 0}, a2 = {0, 0, 0, 0};
    for (int st = 0; st < 32; ++st) {
        for (int idx = tid; idx < 1024; idx += 256) T4[idx] = teg[st * 1024 + idx];
        __syncthreads();
#pragma unroll 4
        for (int s_loc = 0; s_loc < 16; ++s_loc) {
            const float4 tv = T4[s_loc * 64 + e4];
            const int sbase = st * 16 + s_loc;
            const float s0 = scs[(ig * 3 + 0) * 512 + sbase];
            const float s1 = scs[(ig * 3 + 1) * 512 + sbase];
            const float s2 = scs[(ig * 3 + 2) * 512 + sbase];
            a0.x = fmaf(s0, tv.x, a0.x); a0.y = fmaf(s0, tv.y, a0.y);
            a0.z = fmaf(s0, tv.z, a0.z); a0.w = fmaf(s0, tv.w, a0.w);
            a1.x = fmaf(s1, tv.x, a1.x); a1.y = fmaf(s1, tv.y, a1.y);
            a1.z = fmaf(s1, tv.z, a1.z); a1.w = fmaf(s1, tv.w, a1.w);
            a2.x = fmaf(s2, tv.x, a2.x); a2.y = fmaf(s2, tv.y, a2.y);
            a2.z = fmaf(s2, tv.z, a2.z); a2.w = fmaf(s2, tv.w, a2.w);
        }
        __syncthreads();
    }
    float4* fout = (float4*)(feat + (long)b * 153600);
    const float iv0 = invs[ig * 3 + 0], iv1 = invs[ig * 3 + 1], iv2 = invs[ig * 3 + 2];
    float4 w0, w1, w2;
    w0.x = a0.x * iv0; w0.y = a0.y * iv0; w0.z = a0.z * iv0; w0.w = a0.w * iv0;
    w1.x = a1.x * iv1; w1.y = a1.y * iv1; w1.z = a1.z * iv1; w1.w = a1.w * iv1;
    w2.x = a2.x * iv2; w2.y = a2.y * iv2; w2.z = a2.z * iv2; w2.w = a2.w * iv2;
    fout[(l0 + ig * 3 + 0) * 64 + e4] = w0;
    fout[(l0 + ig * 3 + 1) * 64 + e4] = w1;
    fout[(l0 + ig * 3 + 2) * 64 + e4] = w2;
}

// ---------------------------------------------------------------------------
// K7: partial[kc][b][l] = sum_{j in slice} feat[b,j] * Wout[l,j]
//     grid (5 l-tiles of 128, 48 K-slices of 3200) x 256.  Thread: 4b x 4l.
// ---------------------------------------------------------------------------
__global__ __launch_bounds__(256) void k_out_partial(const float* __restrict__ feat,
                                                     const float* __restrict__ Wout,
                                                     float* __restrict__ part) {
    __shared__ float4 Fs[32 * 17];
    __shared__ float4 Ws[128 * 17];
    const int tid = threadIdx.x;
    const int l0 = blockIdx.x * 128;
    const long j0base = (long)blockIdx.y * 3200;
    const int tb = tid & 7, tl = tid >> 3;
    float acc[4][4];
#pragma unroll
    for (int i = 0; i < 4; ++i)
#pragma unroll
        for (int j = 0; j < 4; ++j) acc[i][j] = 0.f;
    for (int cch = 0; cch < 50; ++cch) {
        const long j0 = j0base + cch * 64;
        for (int idx = tid; idx < 512; idx += 256) {
            const int bb = idx >> 4, c = idx & 15;
            Fs[bb * 17 + c] = ((const float4*)(feat + (long)bb * 153600 + j0))[c];
        }
        for (int idx = tid; idx < 2048; idx += 256) {
            const int r = idx >> 4, c = idx & 15;
            const int row = l0 + r;
            Ws[r * 17 + c] = (row < 600)
                ? ((const float4*)(Wout + (long)row * 153600 + j0))[c]
                : make_float4(0.f, 0.f, 0.f, 0.f);
        }
        __syncthreads();
        for (int k4 = 0; k4 < 16; ++k4) {
            float4 fv[4], wv[4];
#pragma unroll
            for (int i = 0; i < 4; ++i) fv[i] = Fs[(tb * 4 + i) * 17 + k4];
#pragma unroll
            for (int j = 0; j < 4; ++j) wv[j] = Ws[(tl * 4 + j) * 17 + k4];
#pragma unroll
            for (int i = 0; i < 4; ++i)
#pragma unroll
                for (int j = 0; j < 4; ++j) acc[i][j] = dot4(fv[i], wv[j], acc[i][j]);
        }
        __syncthreads();
    }
#pragma unroll
    for (int i = 0; i < 4; ++i)
#pragma unroll
        for (int j = 0; j < 4; ++j) {
            const int bidx = tb * 4 + i;
            const int l = l0 + tl * 4 + j;
            if (l < 600)
                part[((long)blockIdx.y * 32 + bidx) * 600 + l] = acc[i][j];
        }
}

// ---------------------------------------------------------------------------
// K8: out[b,l] = sigmoid(sum_kc partial + bout[l])   grid 75 x 256
// ---------------------------------------------------------------------------
__global__ __launch_bounds__(256) void k_finalize(const float* __restrict__ part,
                                                  const float* __restrict__ bout,
                                                  float* __restrict__ out) {
    const int i = blockIdx.x * 256 + threadIdx.x;  // < 19200
    const int l = i % 600;
    float s = 0.f;
    for (int c = 0; c < 48; ++c) s += part[c * 19200 + i];
    const float x = s + bout[l];
    out[i] = 1.f / (1.f + __expf(-x));
}

// ---------------------------------------------------------------------------
extern "C" void kernel_launch(void* const* d_in, const int* in_sizes, int n_in,
                              void* d_out, int out_size, void* d_ws, size_t ws_size,
                              hipStream_t stream) {
    (void)in_sizes; (void)n_in; (void)out_size; (void)ws_size;
    const int*   toks = (const int*)d_in[0];
    const float* th   = (const float*)d_in[1];
    const float* lf   = (const float*)d_in[2];
    const int*   am   = (const int*)d_in[3];
    const float* Wt   = (const float*)d_in[4];
    const float* bt   = (const float*)d_in[5];
    const float* Wl   = (const float*)d_in[6];
    const float* bl   = (const float*)d_in[7];
    const float* WK   = (const float*)d_in[8];
    const float* WQ   = (const float*)d_in[9];
    const float* WV   = (const float*)d_in[10];
    const float* PA   = (const float*)d_in[11];
    const float* PM   = (const float*)d_in[12];
    const float* WA   = (const float*)d_in[13];
    const float* Wout = (const float*)d_in[14];
    const float* bout = (const float*)d_in[15];
    float* ws   = (float*)d_ws;
    float* te   = ws;                   // 4,194,304
    float* le   = te + 4194304;         // 153,600
    float* Kb   = le + 153600;          // 153,600  [h][l][32]
    float* PAQ  = Kb + 153600;          // 153,600
    float* PMV  = PAQ + 153600;         // 153,600
    float* Mb   = PMV + 153600;         // 153,600
    float* feat = Mb + 153600;          // 4,915,200 [b][l*256+e]
    float* part = feat + 4915200;       // 921,600   [48][32][600]
    float* out  = (float*)d_out;

    k_text_enc<<<dim3(1024), dim3(256), 0, stream>>>(th, Wt, bt, te);
    k_le_init<<<dim3(150), dim3(256), 0, stream>>>(lf, Wl, bl, le);
    for (int layer = 0; layer < 2; ++layer) {
        k_qkv<<<dim3(150), dim3(256), 0, stream>>>(le, WK, WQ, WV, PA, PM, Kb, PAQ, PMV);
        k_attn<<<dim3(600, 8), dim3(256), 0, stream>>>(Kb, PAQ, PMV, am, Mb);
        k_update<<<dim3(150), dim3(256), 0, stream>>>(Mb, WA, le);
    }
    k_pool<<<dim3(50, 32), dim3(256), 0, stream>>>(te, le, toks, feat);
    k_out_partial<<<dim3(5, 48), dim3(256), 0, stream>>>(feat, Wout, part);
    k_finalize<<<dim3(75), dim3(256), 0, stream>>>(part, bout, out);
}

// Round 3
// 1523.125 us; speedup vs baseline: 1.2210x; 1.0881x over previous
//
#include <hip/hip_runtime.h>
#include <math.h>

#define NEG_INF (-INFINITY)

// Sizes
// HID=256, H=8, DH=32, N1=60, N2=240, N3=300, L=600, B=32, S=512, DBERT=768

__device__ __forceinline__ float dot4(const float4 a, const float4 b, float acc) {
    acc = fmaf(a.x, b.x, acc);
    acc = fmaf(a.y, b.y, acc);
    acc = fmaf(a.z, b.z, acc);
    acc = fmaf(a.w, b.w, acc);
    return acc;
}

// ---------------------------------------------------------------------------
// K1: text_enc = tanh(text_hidden @ Wt^T + bt)   [16384 x 768] x [256 x 768]^T
// grid 1024 blocks (16 rows each) x 256 threads (one output col each)
// ---------------------------------------------------------------------------
__global__ __launch_bounds__(256) void k_text_enc(const float* __restrict__ th,
                                                  const float* __restrict__ Wt,
                                                  const float* __restrict__ bt,
                                                  float* __restrict__ te) {
    __shared__ __align__(16) float As[16 * 768];   // 48 KB
    const int tid = threadIdx.x;
    const long r0 = (long)blockIdx.x * 16;
    const float4* g = (const float4*)(th + r0 * 768);
    float4* As4 = (float4*)As;
    for (int idx = tid; idx < 16 * 192; idx += 256) As4[idx] = g[idx];
    __syncthreads();
    float acc[16];
#pragma unroll
    for (int r = 0; r < 16; ++r) acc[r] = 0.f;
    const float4* wrow = (const float4*)(Wt + tid * 768);
    for (int j = 0; j < 192; ++j) {
        float4 w = wrow[j];
#pragma unroll
        for (int r = 0; r < 16; ++r) acc[r] = dot4(As4[r * 192 + j], w, acc[r]);
    }
    const float bias = bt[tid];
#pragma unroll
    for (int r = 0; r < 16; ++r)
        te[(r0 + r) * 256 + tid] = tanhf(acc[r] + bias);
}

// ---------------------------------------------------------------------------
// K2: le = label_feat @ Wl^T + bl   [600 x 768] -> [600 x 256]
// grid 150 blocks (4 rows) x 256 threads
// ---------------------------------------------------------------------------
__global__ __launch_bounds__(256) void k_le_init(const float* __restrict__ lf,
                                                 const float* __restrict__ Wl,
                                                 const float* __restrict__ bl,
                                                 float* __restrict__ le) {
    __shared__ __align__(16) float Ls[4 * 768];
    const int tid = threadIdx.x;
    const int l0 = blockIdx.x * 4;
    const float4* g = (const float4*)(lf + (long)l0 * 768);
    float4* Ls4 = (float4*)Ls;
    for (int idx = tid; idx < 4 * 192; idx += 256) Ls4[idx] = g[idx];
    __syncthreads();
    float acc[4] = {0.f, 0.f, 0.f, 0.f};
    const float4* wrow = (const float4*)(Wl + tid * 768);
    for (int j = 0; j < 192; ++j) {
        float4 w = wrow[j];
#pragma unroll
        for (int r = 0; r < 4; ++r) acc[r] = dot4(Ls4[r * 192 + j], w, acc[r]);
    }
    const float bias = bl[tid];
#pragma unroll
    for (int r = 0; r < 4; ++r) le[(l0 + r) * 256 + tid] = acc[r] + bias;
}

// ---------------------------------------------------------------------------
// K3: K/Q/V = per_type(le, W*) ; PAQ = Q·PA^T(per head) ; PMV = V·PM^T
// Layouts: Kb/PAQ/PMV as [h][l][32].  grid 150 (4 rows) x 256
// ---------------------------------------------------------------------------
__global__ __launch_bounds__(256) void k_qkv(const float* __restrict__ le,
                                             const float* __restrict__ WK,
                                             const float* __restrict__ WQ,
                                             const float* __restrict__ WV,
                                             const float* __restrict__ PA,
                                             const float* __restrict__ PM,
                                             float* __restrict__ Kb,
                                             float* __restrict__ PAQ,
                                             float* __restrict__ PMV) {
    __shared__ __align__(16) float les[4 * 256];
    __shared__ __align__(16) float qs[4 * 256];
    __shared__ __align__(16) float vs[4 * 256];
    const int tid = threadIdx.x;
    const int l0 = blockIdx.x * 4;
    const int t3 = (l0 < 60) ? 0 : ((l0 < 300) ? 1 : 2);
#pragma unroll
    for (int r = 0; r < 4; ++r) les[r * 256 + tid] = le[(l0 + r) * 256 + tid];
    __syncthreads();
    float ak[4] = {0, 0, 0, 0}, aq[4] = {0, 0, 0, 0}, av[4] = {0, 0, 0, 0};
    const float4* kw = (const float4*)(WK + t3 * 65536 + tid * 256);
    const float4* qw = (const float4*)(WQ + t3 * 65536 + tid * 256);
    const float4* vw = (const float4*)(WV + t3 * 65536 + tid * 256);
    const float4* le4 = (const float4*)les;
    for (int j = 0; j < 64; ++j) {
        float4 wk = kw[j], wq = qw[j], wv = vw[j];
#pragma unroll
        for (int r = 0; r < 4; ++r) {
            float4 a = le4[r * 64 + j];
            ak[r] = dot4(a, wk, ak[r]);
            aq[r] = dot4(a, wq, aq[r]);
            av[r] = dot4(a, wv, av[r]);
        }
    }
    const int h = tid >> 5, d = tid & 31;
#pragma unroll
    for (int r = 0; r < 4; ++r) {
        Kb[(h * 600 + l0 + r) * 32 + d] = ak[r];
        qs[r * 256 + tid] = aq[r];
        vs[r * 256 + tid] = av[r];
    }
    __syncthreads();
#pragma unroll
    for (int r = 0; r < 4; ++r) {
        float s1 = 0.f, s2 = 0.f;
        for (int d2 = 0; d2 < 32; ++d2) {
            const float pa = PA[d * 32 + d2];   // d == output index e here
            const float pm = PM[d * 32 + d2];
            s1 = fmaf(qs[r * 256 + h * 32 + d2], pa, s1);
            s2 = fmaf(vs[r * 256 + h * 32 + d2], pm, s2);
        }
        PAQ[(h * 600 + l0 + r) * 32 + d] = s1;
        PMV[(h * 600 + l0 + r) * 32 + d] = s2;
    }
}

// ---------------------------------------------------------------------------
// K4: Sc[h,q,:] = scale*PAQ[q,h]·K[:,h] ; zero-block ; +mask ; softmax ;
//     zero Watt on Z ; M[q, h*32+e] = sum_k Watt*PMV.  grid (600, 8) x 256
// ---------------------------------------------------------------------------
__global__ __launch_bounds__(256) void k_attn(const float* __restrict__ Kb,
                                              const float* __restrict__ PAQ,
                                              const float* __restrict__ PMV,
                                              const int* __restrict__ am,
                                              float* __restrict__ Mb) {
    __shared__ float sc[600];
    __shared__ float red[256];
    __shared__ __align__(16) float paqs[32];
    const int tid = threadIdx.x;
    const int q = blockIdx.x, h = blockIdx.y;
    if (tid < 32) paqs[tid] = PAQ[(h * 600 + q) * 32 + tid];
    __syncthreads();
    const float scale = 0.1767766952966369f;  // 1/sqrt(32)
    const bool qb1 = (q < 60), qb3 = (q >= 300);
    float lm = NEG_INF;
    for (int k = tid; k < 600; k += 256) {
        const float4* kr = (const float4*)(Kb + (h * 600 + k) * 32);
        const float4* pr = (const float4*)paqs;
        float dot = 0.f;
#pragma unroll
        for (int j = 0; j < 8; ++j) dot = dot4(pr[j], kr[j], dot);
        const bool zq = (qb1 && k >= 300) || (qb3 && k < 60);
        const float s = (zq ? 0.f : dot * scale) + ((am[q * 600 + k] == 0) ? NEG_INF : 0.f);
        sc[k] = s;
        lm = fmaxf(lm, s);
    }
    red[tid] = lm;
    __syncthreads();
    for (int off = 128; off > 0; off >>= 1) {
        if (tid < off) red[tid] = fmaxf(red[tid], red[tid + off]);
        __syncthreads();
    }
    const float mx = red[0];
    __syncthreads();
    float ls = 0.f;
    for (int k = tid; k < 600; k += 256) {
        const float p = __expf(sc[k] - mx);
        ls += p;   // denominator includes zero-block (pre-zeroed) positions
        const bool zq = (qb1 && k >= 300) || (qb3 && k < 60);
        sc[k] = zq ? 0.f : p;
    }
    red[tid] = ls;
    __syncthreads();
    for (int off = 128; off > 0; off >>= 1) {
        if (tid < off) red[tid] += red[tid + off];
        __syncthreads();
    }
    const float inv = 1.f / red[0];
    __syncthreads();
    const int e = tid & 31, c = tid >> 5;
    float part = 0.f;
    for (int k = c; k < 600; k += 8)
        part = fmaf(sc[k], PMV[(h * 600 + k) * 32 + e], part);
    red[tid] = part;
    __syncthreads();
    if (tid < 32) {
        float tot = 0.f;
#pragma unroll
        for (int cc = 0; cc < 8; ++cc) tot += red[cc * 32 + tid];
        Mb[q * 256 + h * 32 + tid] = tot * inv;
    }
}

// ---------------------------------------------------------------------------
// K5: le += tanh(per_type(M, WA))   grid 150 (4 rows) x 256
// ---------------------------------------------------------------------------
__global__ __launch_bounds__(256) void k_update(const float* __restrict__ Mb,
                                                const float* __restrict__ WA,
                                                float* __restrict__ le) {
    __shared__ __align__(16) float Ms[4 * 256];
    const int tid = threadIdx.x;
    const int l0 = blockIdx.x * 4;
    const int t3 = (l0 < 60) ? 0 : ((l0 < 300) ? 1 : 2);
#pragma unroll
    for (int r = 0; r < 4; ++r) Ms[r * 256 + tid] = Mb[(l0 + r) * 256 + tid];
    __syncthreads();
    float acc[4] = {0, 0, 0, 0};
    const float4* wrow = (const float4*)(WA + t3 * 65536 + tid * 256);
    const float4* M4 = (const float4*)Ms;
    for (int j = 0; j < 64; ++j) {
        float4 w = wrow[j];
#pragma unroll
        for (int r = 0; r < 4; ++r) acc[r] = dot4(M4[r * 64 + j], w, acc[r]);
    }
#pragma unroll
    for (int r = 0; r < 4; ++r) {
        const int i = (l0 + r) * 256 + tid;
        le[i] = tanhf(acc[r]) + le[i];
    }
}

// ---------------------------------------------------------------------------
// K6: fused label->text pooling.  block = (12 l-rows, one b), 256 threads.
//     Phase B: each thread owns 2 s-rows, te straight from global,
//     les via wave-uniform LDS broadcasts.  grid (50, 32)
// ---------------------------------------------------------------------------
__global__ __launch_bounds__(256) void k_pool(const float* __restrict__ te,
                                              const float* __restrict__ le,
                                              const int* __restrict__ toks,
                                              float* __restrict__ feat) {
    __shared__ __align__(16) float les[12 * 256];   // 12 KB
    __shared__ float scs[12 * 512];                 // 24 KB
    __shared__ __align__(16) float Ts[16 * 256];    // 16 KB (Phase D staging)
    __shared__ float red[192];
    __shared__ float mxs[12];
    __shared__ float invs[12];
    const int tid = threadIdx.x;
    const int l0 = blockIdx.x * 12;
    const int b = blockIdx.y;

    // stage les (rows l0..l0+11 are contiguous in le)
    {
        const float4* leg = (const float4*)(le + (long)l0 * 256);
        float4* les4 = (float4*)les;
        for (int idx = tid; idx < 768; idx += 256) les4[idx] = leg[idx];
    }
    __syncthreads();

    // ---- Phase B: scores for s0 = tid, s1 = tid + 256 -------------------
    float acc0[12], acc1[12];
#pragma unroll
    for (int l = 0; l < 12; ++l) { acc0[l] = 0.f; acc1[l] = 0.f; }
    const float4* rowA = (const float4*)(te + (long)b * 131072 + (long)tid * 256);
    const float4* rowB = rowA + 64 * 256;   // +256 rows (64 float4 per row)
    const float4* lp = (const float4*)les;  // [12][64] float4
    for (int j0 = 0; j0 < 64; j0 += 4) {
        float4 ra[4], rb[4];
#pragma unroll
        for (int u = 0; u < 4; ++u) { ra[u] = rowA[j0 + u]; rb[u] = rowB[j0 + u]; }
#pragma unroll
        for (int l = 0; l < 12; ++l) {
#pragma unroll
            for (int u = 0; u < 4; ++u) {
                const float4 lv = lp[l * 64 + j0 + u];   // wave-uniform broadcast
                acc0[l] = dot4(lv, ra[u], acc0[l]);
                acc1[l] = dot4(lv, rb[u], acc1[l]);
            }
        }
    }
    {
        const int t0v = toks[b * 512 + tid];
        const int t1v = toks[b * 512 + 256 + tid];
        const float pm0 = (t0v == 0 || t0v == 101 || t0v == 102) ? NEG_INF : 0.f;
        const float pm1 = (t1v == 0 || t1v == 101 || t1v == 102) ? NEG_INF : 0.f;
#pragma unroll
        for (int l = 0; l < 12; ++l) {
            scs[l * 512 + tid]       = acc0[l] + pm0;
            scs[l * 512 + 256 + tid] = acc1[l] + pm1;
        }
    }
    __syncthreads();

    // ---- Phase C: softmax stats per l-row (max, unnormalized p, 1/denom) --
    const int g = tid >> 4, t16 = tid & 15;
    if (tid < 192) {
        float lm = NEG_INF;
        for (int j = 0; j < 32; ++j) lm = fmaxf(lm, scs[g * 512 + j * 16 + t16]);
        red[tid] = lm;
    }
    __syncthreads();
    if (tid < 12) {
        float m = NEG_INF;
        for (int t = 0; t < 16; ++t) m = fmaxf(m, red[tid * 16 + t]);
        mxs[tid] = m;
    }
    __syncthreads();
    if (tid < 192) {
        const float mval = mxs[g];
        float ls = 0.f;
        for (int j = 0; j < 32; ++j) {
            const int idx = g * 512 + j * 16 + t16;
            const float p = __expf(scs[idx] - mval);
            scs[idx] = p;
            ls += p;
        }
        red[tid] = ls;
    }
    __syncthreads();
    if (tid < 12) {
        float ssum = 0.f;
        for (int t = 0; t < 16; ++t) ssum += red[tid * 16 + t];
        invs[tid] = 1.f / ssum;
    }
    __syncthreads();

    // ---- Phase D: features[l, :] = (sum_s p * te[s,:]) * inv -------------
    const float4* teg = (const float4*)(te + (long)b * 131072);
    float4* T4 = (float4*)Ts;
    const int e4 = tid & 63;       // float4 column
    const int ig = tid >> 6;       // rows ig*3 .. ig*3+2
    float4 a0 = {0, 0, 0, 0}, a1 = {0, 0, 0, 0}, a2 = {0, 0, 0, 0};
    for (int st = 0; st < 32; ++st) {
        for (int idx = tid; idx < 1024; idx += 256) T4[idx] = teg[st * 1024 + idx];
        __syncthreads();
#pragma unroll 4
        for (int s_loc = 0; s_loc < 16; ++s_loc) {
            const float4 tv = T4[s_loc * 64 + e4];
            const int sbase = st * 16 + s_loc;
            const float s0 = scs[(ig * 3 + 0) * 512 + sbase];
            const float s1 = scs[(ig * 3 + 1) * 512 + sbase];
            const float s2 = scs[(ig * 3 + 2) * 512 + sbase];
            a0.x = fmaf(s0, tv.x, a0.x); a0.y = fmaf(s0, tv.y, a0.y);
            a0.z = fmaf(s0, tv.z, a0.z); a0.w = fmaf(s0, tv.w, a0.w);
            a1.x = fmaf(s1, tv.x, a1.x); a1.y = fmaf(s1, tv.y, a1.y);
            a1.z = fmaf(s1, tv.z, a1.z); a1.w = fmaf(s1, tv.w, a1.w);
            a2.x = fmaf(s2, tv.x, a2.x); a2.y = fmaf(s2, tv.y, a2.y);
            a2.z = fmaf(s2, tv.z, a2.z); a2.w = fmaf(s2, tv.w, a2.w);
        }
        __syncthreads();
    }
    float4* fout = (float4*)(feat + (long)b * 153600);
    const float iv0 = invs[ig * 3 + 0], iv1 = invs[ig * 3 + 1], iv2 = invs[ig * 3 + 2];
    float4 w0, w1, w2;
    w0.x = a0.x * iv0; w0.y = a0.y * iv0; w0.z = a0.z * iv0; w0.w = a0.w * iv0;
    w1.x = a1.x * iv1; w1.y = a1.y * iv1; w1.z = a1.z * iv1; w1.w = a1.w * iv1;
    w2.x = a2.x * iv2; w2.y = a2.y * iv2; w2.z = a2.z * iv2; w2.w = a2.w * iv2;
    fout[(l0 + ig * 3 + 0) * 64 + e4] = w0;
    fout[(l0 + ig * 3 + 1) * 64 + e4] = w1;
    fout[(l0 + ig * 3 + 2) * 64 + e4] = w2;
}

// ---------------------------------------------------------------------------
// K7: partial[kc][b][l] = sum_{j in slice} feat[b,j] * Wout[l,j]
//     grid (10 l-tiles of 64, 48 K-slices of 3200) x 256.  Thread: 4b x 2l.
//     Groups of a wave hit consecutive LDS rows; odd f4-stride 17 => start
//     banks 4 apart => conflict-free ds_read_b128.  part stays [48][32][600]
//     (identical workspace footprint to the verified R1 run).
// ---------------------------------------------------------------------------
__global__ __launch_bounds__(256) void k_out_partial(const float* __restrict__ feat,
                                                     const float* __restrict__ Wout,
                                                     float* __restrict__ part) {
    __shared__ float4 Fs[32 * 17];   // 8.5 KB
    __shared__ float4 Ws[64 * 17];   // 17 KB
    const int tid = threadIdx.x;
    const int l0 = blockIdx.x * 64;
    const long j0base = (long)blockIdx.y * 3200;
    const int tb = tid & 7, tl = tid >> 3;   // tb 0..7, tl 0..31
    float acc[4][2];
#pragma unroll
    for (int i = 0; i < 4; ++i)
#pragma unroll
        for (int j = 0; j < 2; ++j) acc[i][j] = 0.f;
    for (int cch = 0; cch < 50; ++cch) {
        const long j0 = j0base + cch * 64;
        for (int idx = tid; idx < 512; idx += 256) {
            const int bb = idx >> 4, c = idx & 15;
            Fs[bb * 17 + c] = ((const float4*)(feat + (long)bb * 153600 + j0))[c];
        }
        for (int idx = tid; idx < 1024; idx += 256) {
            const int r = idx >> 4, c = idx & 15;
            const int row = l0 + r;
            Ws[r * 17 + c] = (row < 600)
                ? ((const float4*)(Wout + (long)row * 153600 + j0))[c]
                : make_float4(0.f, 0.f, 0.f, 0.f);
        }
        __syncthreads();
        for (int k4 = 0; k4 < 16; ++k4) {
            float4 fv[4], wv[2];
#pragma unroll
            for (int i = 0; i < 4; ++i) fv[i] = Fs[(tb + i * 8) * 17 + k4];
#pragma unroll
            for (int j = 0; j < 2; ++j) wv[j] = Ws[(tl + j * 32) * 17 + k4];
#pragma unroll
            for (int i = 0; i < 4; ++i)
#pragma unroll
                for (int j = 0; j < 2; ++j) acc[i][j] = dot4(fv[i], wv[j], acc[i][j]);
        }
        __syncthreads();
    }
#pragma unroll
    for (int i = 0; i < 4; ++i)
#pragma unroll
        for (int j = 0; j < 2; ++j) {
            const int bidx = tb + i * 8;
            const int l = l0 + tl + j * 32;
            if (l < 600)
                part[((long)blockIdx.y * 32 + bidx) * 600 + l] = acc[i][j];
        }
}

// ---------------------------------------------------------------------------
// K8: out[b,l] = sigmoid(sum_kc partial + bout[l])   grid 75 x 256
// ---------------------------------------------------------------------------
__global__ __launch_bounds__(256) void k_finalize(const float* __restrict__ part,
                                                  const float* __restrict__ bout,
                                                  float* __restrict__ out) {
    const int i = blockIdx.x * 256 + threadIdx.x;  // < 19200
    const int l = i % 600;
    float s = 0.f;
    for (int c = 0; c < 48; ++c) s += part[c * 19200 + i];
    const float x = s + bout[l];
    out[i] = 1.f / (1.f + __expf(-x));
}

// ---------------------------------------------------------------------------
extern "C" void kernel_launch(void* const* d_in, const int* in_sizes, int n_in,
                              void* d_out, int out_size, void* d_ws, size_t ws_size,
                              hipStream_t stream) {
    (void)in_sizes; (void)n_in; (void)out_size; (void)ws_size;
    const int*   toks = (const int*)d_in[0];
    const float* th   = (const float*)d_in[1];
    const float* lf   = (const float*)d_in[2];
    const int*   am   = (const int*)d_in[3];
    const float* Wt   = (const float*)d_in[4];
    const float* bt   = (const float*)d_in[5];
    const float* Wl   = (const float*)d_in[6];
    const float* bl   = (const float*)d_in[7];
    const float* WK   = (const float*)d_in[8];
    const float* WQ   = (const float*)d_in[9];
    const float* WV   = (const float*)d_in[10];
    const float* PA   = (const float*)d_in[11];
    const float* PM   = (const float*)d_in[12];
    const float* WA   = (const float*)d_in[13];
    const float* Wout = (const float*)d_in[14];
    const float* bout = (const float*)d_in[15];
    float* ws   = (float*)d_ws;
    float* te   = ws;                   // 4,194,304
    float* le   = te + 4194304;         // 153,600
    float* Kb   = le + 153600;          // 153,600  [h][l][32]
    float* PAQ  = Kb + 153600;          // 153,600
    float* PMV  = PAQ + 153600;         // 153,600
    float* Mb   = PMV + 153600;         // 153,600
    float* feat = Mb + 153600;          // 4,915,200 [b][l*256+e]
    float* part = feat + 4915200;       // 921,600   [48][32][600]
    float* out  = (float*)d_out;

    k_text_enc<<<dim3(1024), dim3(256), 0, stream>>>(th, Wt, bt, te);
    k_le_init<<<dim3(150), dim3(256), 0, stream>>>(lf, Wl, bl, le);
    for (int layer = 0; layer < 2; ++layer) {
        k_qkv<<<dim3(150), dim3(256), 0, stream>>>(le, WK, WQ, WV, PA, PM, Kb, PAQ, PMV);
        k_attn<<<dim3(600, 8), dim3(256), 0, stream>>>(Kb, PAQ, PMV, am, Mb);
        k_update<<<dim3(150), dim3(256), 0, stream>>>(Mb, WA, le);
    }
    k_pool<<<dim3(50, 32), dim3(256), 0, stream>>>(te, le, toks, feat);
    k_out_partial<<<dim3(10, 48), dim3(256), 0, stream>>>(feat, Wout, part);
    k_finalize<<<dim3(75), dim3(256), 0, stream>>>(part, bout, out);
}

// Round 4
// 1426.848 us; speedup vs baseline: 1.3034x; 1.0675x over previous
//
#include <hip/hip_runtime.h>
#include <math.h>

#define NEG_INF (-INFINITY)

// Sizes
// HID=256, H=8, DH=32, N1=60, N2=240, N3=300, L=600, B=32, S=512, DBERT=768

__device__ __forceinline__ float dot4(const float4 a, const float4 b, float acc) {
    acc = fmaf(a.x, b.x, acc);
    acc = fmaf(a.y, b.y, acc);
    acc = fmaf(a.z, b.z, acc);
    acc = fmaf(a.w, b.w, acc);
    return acc;
}

// ---------------------------------------------------------------------------
// K1: text_enc = tanh(text_hidden @ Wt^T + bt)   [16384 x 768] x [256 x 768]^T
// grid 1024 blocks (16 rows each) x 256 threads (one output col each)
// ---------------------------------------------------------------------------
__global__ __launch_bounds__(256) void k_text_enc(const float* __restrict__ th,
                                                  const float* __restrict__ Wt,
                                                  const float* __restrict__ bt,
                                                  float* __restrict__ te) {
    __shared__ __align__(16) float As[16 * 768];   // 48 KB
    const int tid = threadIdx.x;
    const long r0 = (long)blockIdx.x * 16;
    const float4* g = (const float4*)(th + r0 * 768);
    float4* As4 = (float4*)As;
    for (int idx = tid; idx < 16 * 192; idx += 256) As4[idx] = g[idx];
    __syncthreads();
    float acc[16];
#pragma unroll
    for (int r = 0; r < 16; ++r) acc[r] = 0.f;
    const float4* wrow = (const float4*)(Wt + tid * 768);
    for (int j = 0; j < 192; ++j) {
        float4 w = wrow[j];
#pragma unroll
        for (int r = 0; r < 16; ++r) acc[r] = dot4(As4[r * 192 + j], w, acc[r]);
    }
    const float bias = bt[tid];
#pragma unroll
    for (int r = 0; r < 16; ++r)
        te[(r0 + r) * 256 + tid] = tanhf(acc[r] + bias);
}

// ---------------------------------------------------------------------------
// K2: le = label_feat @ Wl^T + bl   [600 x 768] -> [600 x 256]
// grid 150 blocks (4 rows) x 256 threads
// ---------------------------------------------------------------------------
__global__ __launch_bounds__(256) void k_le_init(const float* __restrict__ lf,
                                                 const float* __restrict__ Wl,
                                                 const float* __restrict__ bl,
                                                 float* __restrict__ le) {
    __shared__ __align__(16) float Ls[4 * 768];
    const int tid = threadIdx.x;
    const int l0 = blockIdx.x * 4;
    const float4* g = (const float4*)(lf + (long)l0 * 768);
    float4* Ls4 = (float4*)Ls;
    for (int idx = tid; idx < 4 * 192; idx += 256) Ls4[idx] = g[idx];
    __syncthreads();
    float acc[4] = {0.f, 0.f, 0.f, 0.f};
    const float4* wrow = (const float4*)(Wl + tid * 768);
    for (int j = 0; j < 192; ++j) {
        float4 w = wrow[j];
#pragma unroll
        for (int r = 0; r < 4; ++r) acc[r] = dot4(Ls4[r * 192 + j], w, acc[r]);
    }
    const float bias = bl[tid];
#pragma unroll
    for (int r = 0; r < 4; ++r) le[(l0 + r) * 256 + tid] = acc[r] + bias;
}

// ---------------------------------------------------------------------------
// K3: K/Q/V = per_type(le, W*) ; PAQ = Q·PA^T(per head) ; PMV = V·PM^T
// Layouts: Kb/PAQ/PMV as [h][l][32].  grid 150 (4 rows) x 256
// ---------------------------------------------------------------------------
__global__ __launch_bounds__(256) void k_qkv(const float* __restrict__ le,
                                             const float* __restrict__ WK,
                                             const float* __restrict__ WQ,
                                             const float* __restrict__ WV,
                                             const float* __restrict__ PA,
                                             const float* __restrict__ PM,
                                             float* __restrict__ Kb,
                                             float* __restrict__ PAQ,
                                             float* __restrict__ PMV) {
    __shared__ __align__(16) float les[4 * 256];
    __shared__ __align__(16) float qs[4 * 256];
    __shared__ __align__(16) float vs[4 * 256];
    const int tid = threadIdx.x;
    const int l0 = blockIdx.x * 4;
    const int t3 = (l0 < 60) ? 0 : ((l0 < 300) ? 1 : 2);
#pragma unroll
    for (int r = 0; r < 4; ++r) les[r * 256 + tid] = le[(l0 + r) * 256 + tid];
    __syncthreads();
    float ak[4] = {0, 0, 0, 0}, aq[4] = {0, 0, 0, 0}, av[4] = {0, 0, 0, 0};
    const float4* kw = (const float4*)(WK + t3 * 65536 + tid * 256);
    const float4* qw = (const float4*)(WQ + t3 * 65536 + tid * 256);
    const float4* vw = (const float4*)(WV + t3 * 65536 + tid * 256);
    const float4* le4 = (const float4*)les;
    for (int j = 0; j < 64; ++j) {
        float4 wk = kw[j], wq = qw[j], wv = vw[j];
#pragma unroll
        for (int r = 0; r < 4; ++r) {
            float4 a = le4[r * 64 + j];
            ak[r] = dot4(a, wk, ak[r]);
            aq[r] = dot4(a, wq, aq[r]);
            av[r] = dot4(a, wv, av[r]);
        }
    }
    const int h = tid >> 5, d = tid & 31;
#pragma unroll
    for (int r = 0; r < 4; ++r) {
        Kb[(h * 600 + l0 + r) * 32 + d] = ak[r];
        qs[r * 256 + tid] = aq[r];
        vs[r * 256 + tid] = av[r];
    }
    __syncthreads();
#pragma unroll
    for (int r = 0; r < 4; ++r) {
        float s1 = 0.f, s2 = 0.f;
        for (int d2 = 0; d2 < 32; ++d2) {
            const float pa = PA[d * 32 + d2];   // d == output index e here
            const float pm = PM[d * 32 + d2];
            s1 = fmaf(qs[r * 256 + h * 32 + d2], pa, s1);
            s2 = fmaf(vs[r * 256 + h * 32 + d2], pm, s2);
        }
        PAQ[(h * 600 + l0 + r) * 32 + d] = s1;
        PMV[(h * 600 + l0 + r) * 32 + d] = s2;
    }
}

// ---------------------------------------------------------------------------
// K4: Sc[h,q,:] = scale*PAQ[q,h]·K[:,h] ; zero-block ; +mask ; softmax ;
//     zero Watt on Z ; M[q, h*32+e] = sum_k Watt*PMV.  grid (600, 8) x 256
// ---------------------------------------------------------------------------
__global__ __launch_bounds__(256) void k_attn(const float* __restrict__ Kb,
                                              const float* __restrict__ PAQ,
                                              const float* __restrict__ PMV,
                                              const int* __restrict__ am,
                                              float* __restrict__ Mb) {
    __shared__ float sc[600];
    __shared__ float red[256];
    __shared__ __align__(16) float paqs[32];
    const int tid = threadIdx.x;
    const int q = blockIdx.x, h = blockIdx.y;
    if (tid < 32) paqs[tid] = PAQ[(h * 600 + q) * 32 + tid];
    __syncthreads();
    const float scale = 0.1767766952966369f;  // 1/sqrt(32)
    const bool qb1 = (q < 60), qb3 = (q >= 300);
    float lm = NEG_INF;
    for (int k = tid; k < 600; k += 256) {
        const float4* kr = (const float4*)(Kb + (h * 600 + k) * 32);
        const float4* pr = (const float4*)paqs;
        float dot = 0.f;
#pragma unroll
        for (int j = 0; j < 8; ++j) dot = dot4(pr[j], kr[j], dot);
        const bool zq = (qb1 && k >= 300) || (qb3 && k < 60);
        const float s = (zq ? 0.f : dot * scale) + ((am[q * 600 + k] == 0) ? NEG_INF : 0.f);
        sc[k] = s;
        lm = fmaxf(lm, s);
    }
    red[tid] = lm;
    __syncthreads();
    for (int off = 128; off > 0; off >>= 1) {
        if (tid < off) red[tid] = fmaxf(red[tid], red[tid + off]);
        __syncthreads();
    }
    const float mx = red[0];
    __syncthreads();
    float ls = 0.f;
    for (int k = tid; k < 600; k += 256) {
        const float p = __expf(sc[k] - mx);
        ls += p;   // denominator includes zero-block (pre-zeroed) positions
        const bool zq = (qb1 && k >= 300) || (qb3 && k < 60);
        sc[k] = zq ? 0.f : p;
    }
    red[tid] = ls;
    __syncthreads();
    for (int off = 128; off > 0; off >>= 1) {
        if (tid < off) red[tid] += red[tid + off];
        __syncthreads();
    }
    const float inv = 1.f / red[0];
    __syncthreads();
    const int e = tid & 31, c = tid >> 5;
    float part = 0.f;
    for (int k = c; k < 600; k += 8)
        part = fmaf(sc[k], PMV[(h * 600 + k) * 32 + e], part);
    red[tid] = part;
    __syncthreads();
    if (tid < 32) {
        float tot = 0.f;
#pragma unroll
        for (int cc = 0; cc < 8; ++cc) tot += red[cc * 32 + tid];
        Mb[q * 256 + h * 32 + tid] = tot * inv;
    }
}

// ---------------------------------------------------------------------------
// K5: le += tanh(per_type(M, WA))   grid 150 (4 rows) x 256
// ---------------------------------------------------------------------------
__global__ __launch_bounds__(256) void k_update(const float* __restrict__ Mb,
                                                const float* __restrict__ WA,
                                                float* __restrict__ le) {
    __shared__ __align__(16) float Ms[4 * 256];
    const int tid = threadIdx.x;
    const int l0 = blockIdx.x * 4;
    const int t3 = (l0 < 60) ? 0 : ((l0 < 300) ? 1 : 2);
#pragma unroll
    for (int r = 0; r < 4; ++r) Ms[r * 256 + tid] = Mb[(l0 + r) * 256 + tid];
    __syncthreads();
    float acc[4] = {0, 0, 0, 0};
    const float4* wrow = (const float4*)(WA + t3 * 65536 + tid * 256);
    const float4* M4 = (const float4*)Ms;
    for (int j = 0; j < 64; ++j) {
        float4 w = wrow[j];
#pragma unroll
        for (int r = 0; r < 4; ++r) acc[r] = dot4(M4[r * 64 + j], w, acc[r]);
    }
#pragma unroll
    for (int r = 0; r < 4; ++r) {
        const int i = (l0 + r) * 256 + tid;
        le[i] = tanhf(acc[r]) + le[i];
    }
}

// ---------------------------------------------------------------------------
// K6: fused label->text pooling.  block = (12 l-rows, one b), 256 threads.
//     Phase B: each thread owns 2 s-rows, te straight from global,
//     les via wave-uniform LDS broadcasts.
//     Phase D v3: NO LDS staging, NO barriers — each wave reads te rows
//     direct from global (lane e4 -> coalesced 1KB/instr), scs weights are
//     wave-uniform broadcasts.  LDS ~37.7KB -> 4 blocks/CU.  grid (50, 32)
// ---------------------------------------------------------------------------
__global__ __launch_bounds__(256) void k_pool(const float* __restrict__ te,
                                              const float* __restrict__ le,
                                              const int* __restrict__ toks,
                                              float* __restrict__ feat) {
    __shared__ __align__(16) float les[12 * 256];   // 12 KB
    __shared__ float scs[12 * 512];                 // 24 KB
    __shared__ float red[192];
    __shared__ float mxs[12];
    __shared__ float invs[12];
    const int tid = threadIdx.x;
    const int l0 = blockIdx.x * 12;
    const int b = blockIdx.y;

    // stage les (rows l0..l0+11 are contiguous in le)
    {
        const float4* leg = (const float4*)(le + (long)l0 * 256);
        float4* les4 = (float4*)les;
        for (int idx = tid; idx < 768; idx += 256) les4[idx] = leg[idx];
    }
    __syncthreads();

    // ---- Phase B: scores for s0 = tid, s1 = tid + 256 -------------------
    float acc0[12], acc1[12];
#pragma unroll
    for (int l = 0; l < 12; ++l) { acc0[l] = 0.f; acc1[l] = 0.f; }
    const float4* rowA = (const float4*)(te + (long)b * 131072 + (long)tid * 256);
    const float4* rowB = rowA + 64 * 256;   // +256 rows (64 float4 per row)
    const float4* lp = (const float4*)les;  // [12][64] float4
    for (int j0 = 0; j0 < 64; j0 += 4) {
        float4 ra[4], rb[4];
#pragma unroll
        for (int u = 0; u < 4; ++u) { ra[u] = rowA[j0 + u]; rb[u] = rowB[j0 + u]; }
#pragma unroll
        for (int l = 0; l < 12; ++l) {
#pragma unroll
            for (int u = 0; u < 4; ++u) {
                const float4 lv = lp[l * 64 + j0 + u];   // wave-uniform broadcast
                acc0[l] = dot4(lv, ra[u], acc0[l]);
                acc1[l] = dot4(lv, rb[u], acc1[l]);
            }
        }
    }
    {
        const int t0v = toks[b * 512 + tid];
        const int t1v = toks[b * 512 + 256 + tid];
        const float pm0 = (t0v == 0 || t0v == 101 || t0v == 102) ? NEG_INF : 0.f;
        const float pm1 = (t1v == 0 || t1v == 101 || t1v == 102) ? NEG_INF : 0.f;
#pragma unroll
        for (int l = 0; l < 12; ++l) {
            scs[l * 512 + tid]       = acc0[l] + pm0;
            scs[l * 512 + 256 + tid] = acc1[l] + pm1;
        }
    }
    __syncthreads();

    // ---- Phase C: softmax stats per l-row (max, unnormalized p, 1/denom) --
    const int g = tid >> 4, t16 = tid & 15;
    if (tid < 192) {
        float lm = NEG_INF;
        for (int j = 0; j < 32; ++j) lm = fmaxf(lm, scs[g * 512 + j * 16 + t16]);
        red[tid] = lm;
    }
    __syncthreads();
    if (tid < 12) {
        float m = NEG_INF;
        for (int t = 0; t < 16; ++t) m = fmaxf(m, red[tid * 16 + t]);
        mxs[tid] = m;
    }
    __syncthreads();
    if (tid < 192) {
        const float mval = mxs[g];
        float ls = 0.f;
        for (int j = 0; j < 32; ++j) {
            const int idx = g * 512 + j * 16 + t16;
            const float p = __expf(scs[idx] - mval);
            scs[idx] = p;
            ls += p;
        }
        red[tid] = ls;
    }
    __syncthreads();
    if (tid < 12) {
        float ssum = 0.f;
        for (int t = 0; t < 16; ++t) ssum += red[tid * 16 + t];
        invs[tid] = 1.f / ssum;
    }
    __syncthreads();

    // ---- Phase D: features[l, :] = (sum_s p * te[s,:]) * inv -------------
    // Direct global reads: lane e4 spans 0..63 within each wave -> each
    // teg[s*64+e4] is one fully-coalesced 1KB wave-instruction (L1/L2 hit,
    // waves stream in lockstep).  scs reads are wave-uniform broadcasts.
    const float4* teg = (const float4*)(te + (long)b * 131072);
    const int e4 = tid & 63;       // float4 column
    const int ig = tid >> 6;       // rows ig*3 .. ig*3+2
    const float* p0 = scs + (ig * 3 + 0) * 512;
    const float* p1 = scs + (ig * 3 + 1) * 512;
    const float* p2 = scs + (ig * 3 + 2) * 512;
    float4 a0 = {0, 0, 0, 0}, a1 = {0, 0, 0, 0}, a2 = {0, 0, 0, 0};
    for (int s = 0; s < 512; s += 4) {
        float4 tv[4];
#pragma unroll
        for (int u = 0; u < 4; ++u) tv[u] = teg[(s + u) * 64 + e4];
#pragma unroll
        for (int u = 0; u < 4; ++u) {
            const float s0 = p0[s + u];
            const float s1 = p1[s + u];
            const float s2 = p2[s + u];
            a0.x = fmaf(s0, tv[u].x, a0.x); a0.y = fmaf(s0, tv[u].y, a0.y);
            a0.z = fmaf(s0, tv[u].z, a0.z); a0.w = fmaf(s0, tv[u].w, a0.w);
            a1.x = fmaf(s1, tv[u].x, a1.x); a1.y = fmaf(s1, tv[u].y, a1.y);
            a1.z = fmaf(s1, tv[u].z, a1.z); a1.w = fmaf(s1, tv[u].w, a1.w);
            a2.x = fmaf(s2, tv[u].x, a2.x); a2.y = fmaf(s2, tv[u].y, a2.y);
            a2.z = fmaf(s2, tv[u].z, a2.z); a2.w = fmaf(s2, tv[u].w, a2.w);
        }
    }
    float4* fout = (float4*)(feat + (long)b * 153600);
    const float iv0 = invs[ig * 3 + 0], iv1 = invs[ig * 3 + 1], iv2 = invs[ig * 3 + 2];
    float4 w0, w1, w2;
    w0.x = a0.x * iv0; w0.y = a0.y * iv0; w0.z = a0.z * iv0; w0.w = a0.w * iv0;
    w1.x = a1.x * iv1; w1.y = a1.y * iv1; w1.z = a1.z * iv1; w1.w = a1.w * iv1;
    w2.x = a2.x * iv2; w2.y = a2.y * iv2; w2.z = a2.z * iv2; w2.w = a2.w * iv2;
    fout[(l0 + ig * 3 + 0) * 64 + e4] = w0;
    fout[(l0 + ig * 3 + 1) * 64 + e4] = w1;
    fout[(l0 + ig * 3 + 2) * 64 + e4] = w2;
}

// ---------------------------------------------------------------------------
// K7: partial[kc][b][l] = sum_{j in slice} feat[b,j] * Wout[l,j]
//     grid (10 l-tiles of 64, 48 K-slices of 3200) x 256.  Thread: 4b x 2l.
//     Groups of a wave hit consecutive LDS rows; odd f4-stride 17 => start
//     banks 4 apart => conflict-free ds_read_b128.  part stays [48][32][600]
//     (identical workspace footprint to the verified R1 run).
// ---------------------------------------------------------------------------
__global__ __launch_bounds__(256) void k_out_partial(const float* __restrict__ feat,
                                                     const float* __restrict__ Wout,
                                                     float* __restrict__ part) {
    __shared__ float4 Fs[32 * 17];   // 8.5 KB
    __shared__ float4 Ws[64 * 17];   // 17 KB
    const int tid = threadIdx.x;
    const int l0 = blockIdx.x * 64;
    const long j0base = (long)blockIdx.y * 3200;
    const int tb = tid & 7, tl = tid >> 3;   // tb 0..7, tl 0..31
    float acc[4][2];
#pragma unroll
    for (int i = 0; i < 4; ++i)
#pragma unroll
        for (int j = 0; j < 2; ++j) acc[i][j] = 0.f;
    for (int cch = 0; cch < 50; ++cch) {
        const long j0 = j0base + cch * 64;
        for (int idx = tid; idx < 512; idx += 256) {
            const int bb = idx >> 4, c = idx & 15;
            Fs[bb * 17 + c] = ((const float4*)(feat + (long)bb * 153600 + j0))[c];
        }
        for (int idx = tid; idx < 1024; idx += 256) {
            const int r = idx >> 4, c = idx & 15;
            const int row = l0 + r;
            Ws[r * 17 + c] = (row < 600)
                ? ((const float4*)(Wout + (long)row * 153600 + j0))[c]
                : make_float4(0.f, 0.f, 0.f, 0.f);
        }
        __syncthreads();
        for (int k4 = 0; k4 < 16; ++k4) {
            float4 fv[4], wv[2];
#pragma unroll
            for (int i = 0; i < 4; ++i) fv[i] = Fs[(tb + i * 8) * 17 + k4];
#pragma unroll
            for (int j = 0; j < 2; ++j) wv[j] = Ws[(tl + j * 32) * 17 + k4];
#pragma unroll
            for (int i = 0; i < 4; ++i)
#pragma unroll
                for (int j = 0; j < 2; ++j) acc[i][j] = dot4(fv[i], wv[j], acc[i][j]);
        }
        __syncthreads();
    }
#pragma unroll
    for (int i = 0; i < 4; ++i)
#pragma unroll
        for (int j = 0; j < 2; ++j) {
            const int bidx = tb + i * 8;
            const int l = l0 + tl + j * 32;
            if (l < 600)
                part[((long)blockIdx.y * 32 + bidx) * 600 + l] = acc[i][j];
        }
}

// ---------------------------------------------------------------------------
// K8: out[b,l] = sigmoid(sum_kc partial + bout[l])   grid 75 x 256
// ---------------------------------------------------------------------------
__global__ __launch_bounds__(256) void k_finalize(const float* __restrict__ part,
                                                  const float* __restrict__ bout,
                                                  float* __restrict__ out) {
    const int i = blockIdx.x * 256 + threadIdx.x;  // < 19200
    const int l = i % 600;
    float s = 0.f;
    for (int c = 0; c < 48; ++c) s += part[c * 19200 + i];
    const float x = s + bout[l];
    out[i] = 1.f / (1.f + __expf(-x));
}

// ---------------------------------------------------------------------------
extern "C" void kernel_launch(void* const* d_in, const int* in_sizes, int n_in,
                              void* d_out, int out_size, void* d_ws, size_t ws_size,
                              hipStream_t stream) {
    (void)in_sizes; (void)n_in; (void)out_size; (void)ws_size;
    const int*   toks = (const int*)d_in[0];
    const float* th   = (const float*)d_in[1];
    const float* lf   = (const float*)d_in[2];
    const int*   am   = (const int*)d_in[3];
    const float* Wt   = (const float*)d_in[4];
    const float* bt   = (const float*)d_in[5];
    const float* Wl   = (const float*)d_in[6];
    const float* bl   = (const float*)d_in[7];
    const float* WK   = (const float*)d_in[8];
    const float* WQ   = (const float*)d_in[9];
    const float* WV   = (const float*)d_in[10];
    const float* PA   = (const float*)d_in[11];
    const float* PM   = (const float*)d_in[12];
    const float* WA   = (const float*)d_in[13];
    const float* Wout = (const float*)d_in[14];
    const float* bout = (const float*)d_in[15];
    float* ws   = (float*)d_ws;
    float* te   = ws;                   // 4,194,304
    float* le   = te + 4194304;         // 153,600
    float* Kb   = le + 153600;          // 153,600  [h][l][32]
    float* PAQ  = Kb + 153600;          // 153,600
    float* PMV  = PAQ + 153600;         // 153,600
    float* Mb   = PMV + 153600;         // 153,600
    float* feat = Mb + 153600;          // 4,915,200 [b][l*256+e]
    float* part = feat + 4915200;       // 921,600   [48][32][600]
    float* out  = (float*)d_out;

    k_text_enc<<<dim3(1024), dim3(256), 0, stream>>>(th, Wt, bt, te);
    k_le_init<<<dim3(150), dim3(256), 0, stream>>>(lf, Wl, bl, le);
    for (int layer = 0; layer < 2; ++layer) {
        k_qkv<<<dim3(150), dim3(256), 0, stream>>>(le, WK, WQ, WV, PA, PM, Kb, PAQ, PMV);
        k_attn<<<dim3(600, 8), dim3(256), 0, stream>>>(Kb, PAQ, PMV, am, Mb);
        k_update<<<dim3(150), dim3(256), 0, stream>>>(Mb, WA, le);
    }
    k_pool<<<dim3(50, 32), dim3(256), 0, stream>>>(te, le, toks, feat);
    k_out_partial<<<dim3(10, 48), dim3(256), 0, stream>>>(feat, Wout, part);
    k_finalize<<<dim3(75), dim3(256), 0, stream>>>(part, bout, out);
}

// Round 5
// 1323.868 us; speedup vs baseline: 1.4048x; 1.0778x over previous
//
#include <hip/hip_runtime.h>
#include <math.h>

#define NEG_INF (-INFINITY)

// Sizes
// HID=256, H=8, DH=32, N1=60, N2=240, N3=300, L=600, B=32, S=512, DBERT=768

__device__ __forceinline__ float dot4(const float4 a, const float4 b, float acc) {
    acc = fmaf(a.x, b.x, acc);
    acc = fmaf(a.y, b.y, acc);
    acc = fmaf(a.z, b.z, acc);
    acc = fmaf(a.w, b.w, acc);
    return acc;
}

// ---------------------------------------------------------------------------
// K1: text_enc = tanh(text_hidden @ Wt^T + bt)   [16384 x 768] x [256 x 768]^T
// grid 1024 blocks (16 rows each) x 256 threads (one output col each)
// ---------------------------------------------------------------------------
__global__ __launch_bounds__(256) void k_text_enc(const float* __restrict__ th,
                                                  const float* __restrict__ Wt,
                                                  const float* __restrict__ bt,
                                                  float* __restrict__ te) {
    __shared__ __align__(16) float As[16 * 768];   // 48 KB
    const int tid = threadIdx.x;
    const long r0 = (long)blockIdx.x * 16;
    const float4* g = (const float4*)(th + r0 * 768);
    float4* As4 = (float4*)As;
    for (int idx = tid; idx < 16 * 192; idx += 256) As4[idx] = g[idx];
    __syncthreads();
    float acc[16];
#pragma unroll
    for (int r = 0; r < 16; ++r) acc[r] = 0.f;
    const float4* wrow = (const float4*)(Wt + tid * 768);
    for (int j = 0; j < 192; ++j) {
        float4 w = wrow[j];
#pragma unroll
        for (int r = 0; r < 16; ++r) acc[r] = dot4(As4[r * 192 + j], w, acc[r]);
    }
    const float bias = bt[tid];
#pragma unroll
    for (int r = 0; r < 16; ++r)
        te[(r0 + r) * 256 + tid] = tanhf(acc[r] + bias);
}

// ---------------------------------------------------------------------------
// K2: le = label_feat @ Wl^T + bl   [600 x 768] -> [600 x 256]
// grid 150 blocks (4 rows) x 256 threads
// ---------------------------------------------------------------------------
__global__ __launch_bounds__(256) void k_le_init(const float* __restrict__ lf,
                                                 const float* __restrict__ Wl,
                                                 const float* __restrict__ bl,
                                                 float* __restrict__ le) {
    __shared__ __align__(16) float Ls[4 * 768];
    const int tid = threadIdx.x;
    const int l0 = blockIdx.x * 4;
    const float4* g = (const float4*)(lf + (long)l0 * 768);
    float4* Ls4 = (float4*)Ls;
    for (int idx = tid; idx < 4 * 192; idx += 256) Ls4[idx] = g[idx];
    __syncthreads();
    float acc[4] = {0.f, 0.f, 0.f, 0.f};
    const float4* wrow = (const float4*)(Wl + tid * 768);
    for (int j = 0; j < 192; ++j) {
        float4 w = wrow[j];
#pragma unroll
        for (int r = 0; r < 4; ++r) acc[r] = dot4(Ls4[r * 192 + j], w, acc[r]);
    }
    const float bias = bl[tid];
#pragma unroll
    for (int r = 0; r < 4; ++r) le[(l0 + r) * 256 + tid] = acc[r] + bias;
}

// ---------------------------------------------------------------------------
// K3: K/Q/V = per_type(le, W*) ; PAQ = Q·PA^T(per head) ; PMV = V·PM^T
// Layouts: Kb/PAQ/PMV as [h][l][32].  grid 150 (4 rows) x 256
// ---------------------------------------------------------------------------
__global__ __launch_bounds__(256) void k_qkv(const float* __restrict__ le,
                                             const float* __restrict__ WK,
                                             const float* __restrict__ WQ,
                                             const float* __restrict__ WV,
                                             const float* __restrict__ PA,
                                             const float* __restrict__ PM,
                                             float* __restrict__ Kb,
                                             float* __restrict__ PAQ,
                                             float* __restrict__ PMV) {
    __shared__ __align__(16) float les[4 * 256];
    __shared__ __align__(16) float qs[4 * 256];
    __shared__ __align__(16) float vs[4 * 256];
    const int tid = threadIdx.x;
    const int l0 = blockIdx.x * 4;
    const int t3 = (l0 < 60) ? 0 : ((l0 < 300) ? 1 : 2);
#pragma unroll
    for (int r = 0; r < 4; ++r) les[r * 256 + tid] = le[(l0 + r) * 256 + tid];
    __syncthreads();
    float ak[4] = {0, 0, 0, 0}, aq[4] = {0, 0, 0, 0}, av[4] = {0, 0, 0, 0};
    const float4* kw = (const float4*)(WK + t3 * 65536 + tid * 256);
    const float4* qw = (const float4*)(WQ + t3 * 65536 + tid * 256);
    const float4* vw = (const float4*)(WV + t3 * 65536 + tid * 256);
    const float4* le4 = (const float4*)les;
    for (int j = 0; j < 64; ++j) {
        float4 wk = kw[j], wq = qw[j], wv = vw[j];
#pragma unroll
        for (int r = 0; r < 4; ++r) {
            float4 a = le4[r * 64 + j];
            ak[r] = dot4(a, wk, ak[r]);
            aq[r] = dot4(a, wq, aq[r]);
            av[r] = dot4(a, wv, av[r]);
        }
    }
    const int h = tid >> 5, d = tid & 31;
#pragma unroll
    for (int r = 0; r < 4; ++r) {
        Kb[(h * 600 + l0 + r) * 32 + d] = ak[r];
        qs[r * 256 + tid] = aq[r];
        vs[r * 256 + tid] = av[r];
    }
    __syncthreads();
#pragma unroll
    for (int r = 0; r < 4; ++r) {
        float s1 = 0.f, s2 = 0.f;
        for (int d2 = 0; d2 < 32; ++d2) {
            const float pa = PA[d * 32 + d2];   // d == output index e here
            const float pm = PM[d * 32 + d2];
            s1 = fmaf(qs[r * 256 + h * 32 + d2], pa, s1);
            s2 = fmaf(vs[r * 256 + h * 32 + d2], pm, s2);
        }
        PAQ[(h * 600 + l0 + r) * 32 + d] = s1;
        PMV[(h * 600 + l0 + r) * 32 + d] = s2;
    }
}

// ---------------------------------------------------------------------------
// K4: Sc[h,q,:] = scale*PAQ[q,h]·K[:,h] ; zero-block ; +mask ; softmax ;
//     zero Watt on Z ; M[q, h*32+e] = sum_k Watt*PMV.  grid (600, 8) x 256
// ---------------------------------------------------------------------------
__global__ __launch_bounds__(256) void k_attn(const float* __restrict__ Kb,
                                              const float* __restrict__ PAQ,
                                              const float* __restrict__ PMV,
                                              const int* __restrict__ am,
                                              float* __restrict__ Mb) {
    __shared__ float sc[600];
    __shared__ float red[256];
    __shared__ __align__(16) float paqs[32];
    const int tid = threadIdx.x;
    const int q = blockIdx.x, h = blockIdx.y;
    if (tid < 32) paqs[tid] = PAQ[(h * 600 + q) * 32 + tid];
    __syncthreads();
    const float scale = 0.1767766952966369f;  // 1/sqrt(32)
    const bool qb1 = (q < 60), qb3 = (q >= 300);
    float lm = NEG_INF;
    for (int k = tid; k < 600; k += 256) {
        const float4* kr = (const float4*)(Kb + (h * 600 + k) * 32);
        const float4* pr = (const float4*)paqs;
        float dot = 0.f;
#pragma unroll
        for (int j = 0; j < 8; ++j) dot = dot4(pr[j], kr[j], dot);
        const bool zq = (qb1 && k >= 300) || (qb3 && k < 60);
        const float s = (zq ? 0.f : dot * scale) + ((am[q * 600 + k] == 0) ? NEG_INF : 0.f);
        sc[k] = s;
        lm = fmaxf(lm, s);
    }
    red[tid] = lm;
    __syncthreads();
    for (int off = 128; off > 0; off >>= 1) {
        if (tid < off) red[tid] = fmaxf(red[tid], red[tid + off]);
        __syncthreads();
    }
    const float mx = red[0];
    __syncthreads();
    float ls = 0.f;
    for (int k = tid; k < 600; k += 256) {
        const float p = __expf(sc[k] - mx);
        ls += p;   // denominator includes zero-block (pre-zeroed) positions
        const bool zq = (qb1 && k >= 300) || (qb3 && k < 60);
        sc[k] = zq ? 0.f : p;
    }
    red[tid] = ls;
    __syncthreads();
    for (int off = 128; off > 0; off >>= 1) {
        if (tid < off) red[tid] += red[tid + off];
        __syncthreads();
    }
    const float inv = 1.f / red[0];
    __syncthreads();
    const int e = tid & 31, c = tid >> 5;
    float part = 0.f;
    for (int k = c; k < 600; k += 8)
        part = fmaf(sc[k], PMV[(h * 600 + k) * 32 + e], part);
    red[tid] = part;
    __syncthreads();
    if (tid < 32) {
        float tot = 0.f;
#pragma unroll
        for (int cc = 0; cc < 8; ++cc) tot += red[cc * 32 + tid];
        Mb[q * 256 + h * 32 + tid] = tot * inv;
    }
}

// ---------------------------------------------------------------------------
// K5: le += tanh(per_type(M, WA))   grid 150 (4 rows) x 256
// ---------------------------------------------------------------------------
__global__ __launch_bounds__(256) void k_update(const float* __restrict__ Mb,
                                                const float* __restrict__ WA,
                                                float* __restrict__ le) {
    __shared__ __align__(16) float Ms[4 * 256];
    const int tid = threadIdx.x;
    const int l0 = blockIdx.x * 4;
    const int t3 = (l0 < 60) ? 0 : ((l0 < 300) ? 1 : 2);
#pragma unroll
    for (int r = 0; r < 4; ++r) Ms[r * 256 + tid] = Mb[(l0 + r) * 256 + tid];
    __syncthreads();
    float acc[4] = {0, 0, 0, 0};
    const float4* wrow = (const float4*)(WA + t3 * 65536 + tid * 256);
    const float4* M4 = (const float4*)Ms;
    for (int j = 0; j < 64; ++j) {
        float4 w = wrow[j];
#pragma unroll
        for (int r = 0; r < 4; ++r) acc[r] = dot4(M4[r * 64 + j], w, acc[r]);
    }
#pragma unroll
    for (int r = 0; r < 4; ++r) {
        const int i = (l0 + r) * 256 + tid;
        le[i] = tanhf(acc[r]) + le[i];
    }
}

// ---------------------------------------------------------------------------
// K6: fused label->text pooling.  block = (12 l-rows, one b), 256 threads.
//     Phase B: each thread owns 2 s-rows, te straight from global,
//     les via wave-uniform LDS broadcasts.
//     Phase D: no LDS staging/barriers — direct coalesced global te reads,
//     scs weights are wave-uniform broadcasts.  grid (50, 32)
// ---------------------------------------------------------------------------
__global__ __launch_bounds__(256) void k_pool(const float* __restrict__ te,
                                              const float* __restrict__ le,
                                              const int* __restrict__ toks,
                                              float* __restrict__ feat) {
    __shared__ __align__(16) float les[12 * 256];   // 12 KB
    __shared__ float scs[12 * 512];                 // 24 KB
    __shared__ float red[192];
    __shared__ float mxs[12];
    __shared__ float invs[12];
    const int tid = threadIdx.x;
    const int l0 = blockIdx.x * 12;
    const int b = blockIdx.y;

    // stage les (rows l0..l0+11 are contiguous in le)
    {
        const float4* leg = (const float4*)(le + (long)l0 * 256);
        float4* les4 = (float4*)les;
        for (int idx = tid; idx < 768; idx += 256) les4[idx] = leg[idx];
    }
    __syncthreads();

    // ---- Phase B: scores for s0 = tid, s1 = tid + 256 -------------------
    float acc0[12], acc1[12];
#pragma unroll
    for (int l = 0; l < 12; ++l) { acc0[l] = 0.f; acc1[l] = 0.f; }
    const float4* rowA = (const float4*)(te + (long)b * 131072 + (long)tid * 256);
    const float4* rowB = rowA + 64 * 256;   // +256 rows (64 float4 per row)
    const float4* lp = (const float4*)les;  // [12][64] float4
    for (int j0 = 0; j0 < 64; j0 += 4) {
        float4 ra[4], rb[4];
#pragma unroll
        for (int u = 0; u < 4; ++u) { ra[u] = rowA[j0 + u]; rb[u] = rowB[j0 + u]; }
#pragma unroll
        for (int l = 0; l < 12; ++l) {
#pragma unroll
            for (int u = 0; u < 4; ++u) {
                const float4 lv = lp[l * 64 + j0 + u];   // wave-uniform broadcast
                acc0[l] = dot4(lv, ra[u], acc0[l]);
                acc1[l] = dot4(lv, rb[u], acc1[l]);
            }
        }
    }
    {
        const int t0v = toks[b * 512 + tid];
        const int t1v = toks[b * 512 + 256 + tid];
        const float pm0 = (t0v == 0 || t0v == 101 || t0v == 102) ? NEG_INF : 0.f;
        const float pm1 = (t1v == 0 || t1v == 101 || t1v == 102) ? NEG_INF : 0.f;
#pragma unroll
        for (int l = 0; l < 12; ++l) {
            scs[l * 512 + tid]       = acc0[l] + pm0;
            scs[l * 512 + 256 + tid] = acc1[l] + pm1;
        }
    }
    __syncthreads();

    // ---- Phase C: softmax stats per l-row (max, unnormalized p, 1/denom) --
    const int g = tid >> 4, t16 = tid & 15;
    if (tid < 192) {
        float lm = NEG_INF;
        for (int j = 0; j < 32; ++j) lm = fmaxf(lm, scs[g * 512 + j * 16 + t16]);
        red[tid] = lm;
    }
    __syncthreads();
    if (tid < 12) {
        float m = NEG_INF;
        for (int t = 0; t < 16; ++t) m = fmaxf(m, red[tid * 16 + t]);
        mxs[tid] = m;
    }
    __syncthreads();
    if (tid < 192) {
        const float mval = mxs[g];
        float ls = 0.f;
        for (int j = 0; j < 32; ++j) {
            const int idx = g * 512 + j * 16 + t16;
            const float p = __expf(scs[idx] - mval);
            scs[idx] = p;
            ls += p;
        }
        red[tid] = ls;
    }
    __syncthreads();
    if (tid < 12) {
        float ssum = 0.f;
        for (int t = 0; t < 16; ++t) ssum += red[tid * 16 + t];
        invs[tid] = 1.f / ssum;
    }
    __syncthreads();

    // ---- Phase D: features[l, :] = (sum_s p * te[s,:]) * inv -------------
    const float4* teg = (const float4*)(te + (long)b * 131072);
    const int e4 = tid & 63;       // float4 column
    const int ig = tid >> 6;       // rows ig*3 .. ig*3+2
    const float* p0 = scs + (ig * 3 + 0) * 512;
    const float* p1 = scs + (ig * 3 + 1) * 512;
    const float* p2 = scs + (ig * 3 + 2) * 512;
    float4 a0 = {0, 0, 0, 0}, a1 = {0, 0, 0, 0}, a2 = {0, 0, 0, 0};
    for (int s = 0; s < 512; s += 4) {
        float4 tv[4];
#pragma unroll
        for (int u = 0; u < 4; ++u) tv[u] = teg[(s + u) * 64 + e4];
#pragma unroll
        for (int u = 0; u < 4; ++u) {
            const float s0 = p0[s + u];
            const float s1 = p1[s + u];
            const float s2 = p2[s + u];
            a0.x = fmaf(s0, tv[u].x, a0.x); a0.y = fmaf(s0, tv[u].y, a0.y);
            a0.z = fmaf(s0, tv[u].z, a0.z); a0.w = fmaf(s0, tv[u].w, a0.w);
            a1.x = fmaf(s1, tv[u].x, a1.x); a1.y = fmaf(s1, tv[u].y, a1.y);
            a1.z = fmaf(s1, tv[u].z, a1.z); a1.w = fmaf(s1, tv[u].w, a1.w);
            a2.x = fmaf(s2, tv[u].x, a2.x); a2.y = fmaf(s2, tv[u].y, a2.y);
            a2.z = fmaf(s2, tv[u].z, a2.z); a2.w = fmaf(s2, tv[u].w, a2.w);
        }
    }
    float4* fout = (float4*)(feat + (long)b * 153600);
    const float iv0 = invs[ig * 3 + 0], iv1 = invs[ig * 3 + 1], iv2 = invs[ig * 3 + 2];
    float4 w0, w1, w2;
    w0.x = a0.x * iv0; w0.y = a0.y * iv0; w0.z = a0.z * iv0; w0.w = a0.w * iv0;
    w1.x = a1.x * iv1; w1.y = a1.y * iv1; w1.z = a1.z * iv1; w1.w = a1.w * iv1;
    w2.x = a2.x * iv2; w2.y = a2.y * iv2; w2.z = a2.z * iv2; w2.w = a2.w * iv2;
    fout[(l0 + ig * 3 + 0) * 64 + e4] = w0;
    fout[(l0 + ig * 3 + 1) * 64 + e4] = w1;
    fout[(l0 + ig * 3 + 2) * 64 + e4] = w2;
}

// ---------------------------------------------------------------------------
// K7: partial[kc][b][l] = sum_{j in slice} feat[b,j] * Wout[l,j]
//     grid (10 l-tiles of 64, 96 K-slices of 1600) x 256.  Thread: 4b x 2l.
//     part[96][32][600] is ALIASED onto te's region (te dead after k_pool),
//     so the occupancy fix costs zero extra workspace.
// ---------------------------------------------------------------------------
__global__ __launch_bounds__(256) void k_out_partial(const float* __restrict__ feat,
                                                     const float* __restrict__ Wout,
                                                     float* __restrict__ part) {
    __shared__ float4 Fs[32 * 17];   // 8.5 KB
    __shared__ float4 Ws[64 * 17];   // 17 KB
    const int tid = threadIdx.x;
    const int l0 = blockIdx.x * 64;
    const long j0base = (long)blockIdx.y * 1600;
    const int tb = tid & 7, tl = tid >> 3;   // tb 0..7, tl 0..31
    float acc[4][2];
#pragma unroll
    for (int i = 0; i < 4; ++i)
#pragma unroll
        for (int j = 0; j < 2; ++j) acc[i][j] = 0.f;
    for (int cch = 0; cch < 25; ++cch) {
        const long j0 = j0base + cch * 64;
        for (int idx = tid; idx < 512; idx += 256) {
            const int bb = idx >> 4, c = idx & 15;
            Fs[bb * 17 + c] = ((const float4*)(feat + (long)bb * 153600 + j0))[c];
        }
        for (int idx = tid; idx < 1024; idx += 256) {
            const int r = idx >> 4, c = idx & 15;
            const int row = l0 + r;
            Ws[r * 17 + c] = (row < 600)
                ? ((const float4*)(Wout + (long)row * 153600 + j0))[c]
                : make_float4(0.f, 0.f, 0.f, 0.f);
        }
        __syncthreads();
        for (int k4 = 0; k4 < 16; ++k4) {
            float4 fv[4], wv[2];
#pragma unroll
            for (int i = 0; i < 4; ++i) fv[i] = Fs[(tb + i * 8) * 17 + k4];
#pragma unroll
            for (int j = 0; j < 2; ++j) wv[j] = Ws[(tl + j * 32) * 17 + k4];
#pragma unroll
            for (int i = 0; i < 4; ++i)
#pragma unroll
                for (int j = 0; j < 2; ++j) acc[i][j] = dot4(fv[i], wv[j], acc[i][j]);
        }
        __syncthreads();
    }
#pragma unroll
    for (int i = 0; i < 4; ++i)
#pragma unroll
        for (int j = 0; j < 2; ++j) {
            const int bidx = tb + i * 8;
            const int l = l0 + tl + j * 32;
            if (l < 600)
                part[((long)blockIdx.y * 32 + bidx) * 600 + l] = acc[i][j];
        }
}

// ---------------------------------------------------------------------------
// K8: out[b,l] = sigmoid(sum_kc partial + bout[l])   grid 75 x 256
// ---------------------------------------------------------------------------
__global__ __launch_bounds__(256) void k_finalize(const float* __restrict__ part,
                                                  const float* __restrict__ bout,
                                                  float* __restrict__ out) {
    const int i = blockIdx.x * 256 + threadIdx.x;  // < 19200
    const int l = i % 600;
    float s = 0.f;
    for (int c = 0; c < 96; ++c) s += part[c * 19200 + i];
    const float x = s + bout[l];
    out[i] = 1.f / (1.f + __expf(-x));
}

// ---------------------------------------------------------------------------
extern "C" void kernel_launch(void* const* d_in, const int* in_sizes, int n_in,
                              void* d_out, int out_size, void* d_ws, size_t ws_size,
                              hipStream_t stream) {
    (void)in_sizes; (void)n_in; (void)out_size; (void)ws_size;
    const int*   toks = (const int*)d_in[0];
    const float* th   = (const float*)d_in[1];
    const float* lf   = (const float*)d_in[2];
    const int*   am   = (const int*)d_in[3];
    const float* Wt   = (const float*)d_in[4];
    const float* bt   = (const float*)d_in[5];
    const float* Wl   = (const float*)d_in[6];
    const float* bl   = (const float*)d_in[7];
    const float* WK   = (const float*)d_in[8];
    const float* WQ   = (const float*)d_in[9];
    const float* WV   = (const float*)d_in[10];
    const float* PA   = (const float*)d_in[11];
    const float* PM   = (const float*)d_in[12];
    const float* WA   = (const float*)d_in[13];
    const float* Wout = (const float*)d_in[14];
    const float* bout = (const float*)d_in[15];
    float* ws   = (float*)d_ws;
    float* te   = ws;                   // 4,194,304 (dead after k_pool)
    float* le   = te + 4194304;         // 153,600
    float* Kb   = le + 153600;          // 153,600  [h][l][32]
    float* PAQ  = Kb + 153600;          // 153,600
    float* PMV  = PAQ + 153600;         // 153,600
    float* Mb   = PMV + 153600;         // 153,600
    float* feat = Mb + 153600;          // 4,915,200 [b][l*256+e]
    float* part = te;                   // 1,843,200 [96][32][600] — ALIASED onto te
    float* out  = (float*)d_out;

    k_text_enc<<<dim3(1024), dim3(256), 0, stream>>>(th, Wt, bt, te);
    k_le_init<<<dim3(150), dim3(256), 0, stream>>>(lf, Wl, bl, le);
    for (int layer = 0; layer < 2; ++layer) {
        k_qkv<<<dim3(150), dim3(256), 0, stream>>>(le, WK, WQ, WV, PA, PM, Kb, PAQ, PMV);
        k_attn<<<dim3(600, 8), dim3(256), 0, stream>>>(Kb, PAQ, PMV, am, Mb);
        k_update<<<dim3(150), dim3(256), 0, stream>>>(Mb, WA, le);
    }
    k_pool<<<dim3(50, 32), dim3(256), 0, stream>>>(te, le, toks, feat);
    k_out_partial<<<dim3(10, 96), dim3(256), 0, stream>>>(feat, Wout, part);
    k_finalize<<<dim3(75), dim3(256), 0, stream>>>(part, bout, out);
}